// Round 4
// baseline (216.290 us; speedup 1.0000x reference)
//
#include <hip/hip_runtime.h>

#define NG 40

// ---------- pre-kernel: K2[g] = k[g] (full 2-D conv) k[g], 9x9 per group ----------
// Two circular cross-correlations with k == one circular cross-correlation with K2.
__global__ void compose_k2(const float* __restrict__ kernels, float* __restrict__ k2) {
    int t = blockIdx.x * 256 + threadIdx.x;          // 40*81 = 3240 outputs
    if (t >= NG * 81) return;
    int gi = t / 81, r = t - gi * 81;
    int a = r / 9, b = r - a * 9;
    const float* k = kernels + gi * 25;
    float s = 0.f;
    for (int i = 0; i < 5; ++i) {
        int p = a - i;
        if (p < 0 || p > 4) continue;
        for (int j = 0; j < 5; ++j) {
            int q = b - j;
            if (q < 0 || q > 4) continue;
            s += k[i * 5 + j] * k[p * 5 + q];
        }
    }
    k2[t] = s;
}

__device__ __forceinline__ void async_copy16(const float* gsrc, float* lds_dst) {
    __builtin_amdgcn_global_load_lds(
        (const __attribute__((address_space(1))) void*)(gsrc),
        (__attribute__((address_space(3))) void*)(lds_dst),
        16, 0, 0);
}

// ---------- main kernel: one 56x56 plane per block (R2 structure + swizzle) ----------
// LDS tile: 64 padded rows x 16 slots of 16B (packed stride 64 floats, halo 4, circular).
// XOR swizzle: data segment s of padded row r lives at slot (s&8) | ((s&7)^(r&7)).
// Staging keeps global_load_lds lane-contiguity by permuting the SOURCE column.
// Thread p (<112) computes a 7-row x 4-col patch: rows 7*(p/14).., cols 4*(p%14)..
template <bool USE_WS>
__global__ __launch_bounds__(128, 3)
void conv9_main(const float* __restrict__ x, const float* __restrict__ kdata,
                const int* __restrict__ g, float* __restrict__ out) {
    __shared__ float tile[64 * 64];
    __shared__ float k9s[81];

    const int tid = threadIdx.x;
    const int bx  = blockIdx.x;          // == b*64 + channel, 8192 blocks
    const int b   = bx >> 6;

    int gi = g[b] % NG; if (gi < 0) gi += NG;

    // --- stage plane via async global->LDS, 16B/lane, swizzled source column ---
    const float* xp = x + (size_t)bx * 3136;
    #pragma unroll
    for (int m = 0; m < 8; ++m) {
        int idx = m * 128 + tid;         // 0..1023
        int pr  = idx >> 4;              // padded row 0..63
        int j   = idx & 15;              // destination slot
        int s   = (j & 8) | ((j & 7) ^ (pr & 7));   // data segment stored in slot j
        int sr = pr - 4;    if (sr < 0) sr += 56; if (sr >= 56) sr -= 56;
        int sc = s * 4 - 4; if (sc < 0) sc += 56; if (sc >= 56) sc -= 56;
        async_copy16(xp + sr * 56 + sc, tile + idx * 4);
    }

    // --- composed 9x9 taps ---
    float kk[81];
    if (USE_WS) {
        const float* kp = kdata + gi * 81;  // wave-uniform -> scalar loads
        #pragma unroll
        for (int i = 0; i < 81; ++i) kk[i] = kp[i];
    } else {
        if (tid < 81) {
            const float* k = kdata + gi * 25;
            int a = tid / 9, bb = tid - a * 9;
            float s = 0.f;
            for (int i = 0; i < 5; ++i) {
                int p = a - i;
                if (p < 0 || p > 4) continue;
                for (int j = 0; j < 5; ++j) {
                    int q = bb - j;
                    if (q < 0 || q > 4) continue;
                    s += k[i * 5 + j] * k[p * 5 + q];
                }
            }
            k9s[tid] = s;
        }
    }

    // Explicit drain of the async global->LDS DMA before the barrier: do not
    // rely on the compiler's implicit vmcnt(0)-before-s_barrier (race seen R3).
    asm volatile("s_waitcnt vmcnt(0)" ::: "memory");
    __syncthreads();

    if (!USE_WS) {
        #pragma unroll
        for (int i = 0; i < 81; ++i) kk[i] = k9s[i];   // broadcast, conflict-free
    }

    const int p = tid;
    if (p < 112) {
        const int pr = p / 14;            // 0..7  -> q = 7*pr
        const int pc = p - pr * 14;       // 0..13 -> c = 4*pc
        const int q  = 7 * pr;
        const int c  = 4 * pc;

        float acc[7][4] = {};

        #pragma unroll
        for (int h = 0; h < 15; ++h) {
            const int rr  = q + h;        // padded row
            const int key = rr & 7;
            float w0[12];
            #pragma unroll
            for (int i = 0; i < 3; ++i) {
                int s    = pc + i;        // data segment wanted
                int slot = (s & 8) | ((s & 7) ^ key);
                const float4 v = *(const float4*)(tile + rr * 64 + slot * 4);
                w0[i * 4 + 0] = v.x; w0[i * 4 + 1] = v.y;
                w0[i * 4 + 2] = v.z; w0[i * 4 + 3] = v.w;
            }
            #pragma unroll
            for (int ro = 0; ro < 7; ++ro) {
                const int v = h - ro;     // kernel row tap (folded at compile time)
                if (v < 0 || v > 8) continue;
                #pragma unroll
                for (int j = 0; j < 4; ++j) {
                    #pragma unroll
                    for (int u = 0; u < 9; ++u)
                        acc[ro][j] += w0[j + u] * kk[v * 9 + u];
                }
            }
        }

        float* op = out + (size_t)bx * 3136 + q * 56 + c;
        #pragma unroll
        for (int ro = 0; ro < 7; ++ro)
            *(float4*)(op + ro * 56) =
                make_float4(acc[ro][0], acc[ro][1], acc[ro][2], acc[ro][3]);
    }
}

extern "C" void kernel_launch(void* const* d_in, const int* in_sizes, int n_in,
                              void* d_out, int out_size, void* d_ws, size_t ws_size,
                              hipStream_t stream) {
    const float* x    = (const float*)d_in[0];
    const float* kern = (const float*)d_in[1];
    const int*   g    = (const int*)d_in[2];
    float*       out  = (float*)d_out;

    const bool use_ws = ws_size >= (size_t)(NG * 81 * sizeof(float));
    if (use_ws) {
        compose_k2<<<dim3((NG * 81 + 255) / 256), dim3(256), 0, stream>>>(kern, (float*)d_ws);
        conv9_main<true><<<dim3(8192), dim3(128), 0, stream>>>(x, (const float*)d_ws, g, out);
    } else {
        conv9_main<false><<<dim3(8192), dim3(128), 0, stream>>>(x, kern, g, out);
    }
}